// Round 1
// baseline (2939.556 us; speedup 1.0000x reference)
//
#include <hip/hip_runtime.h>

#define FD 128
#define BN_EPS 1e-5f

// ---------------------------------------------------------------------------
// Edge-index format probe: harness doc says integer inputs arrive as int32,
// but the reference uses int64. Detect at runtime (deterministic): if the
// first 2E int32 words have all odd words == 0, treat as int64.
// ---------------------------------------------------------------------------
__global__ __launch_bounds__(256) void detect_kernel(const int* __restrict__ ei,
                                                     int n32, int* flag) {
    __shared__ int any;
    if (threadIdx.x == 0) any = 0;
    __syncthreads();
    int limit = n32 < 4096 ? n32 : 4096;
    int found = 0;
    for (int i = threadIdx.x * 2 + 1; i < limit; i += 512) {
        if (ei[i] != 0) { found = 1; break; }
    }
    if (found) atomicOr(&any, 1);
    __syncthreads();
    if (threadIdx.x == 0) flag[0] = any ? 0 : 1;   // 1 => int64 layout
}

__device__ __forceinline__ int edge_get(const void* ei, int is64, size_t idx) {
    return is64 ? (int)((const long long*)ei)[idx] : ((const int*)ei)[idx];
}

// deg[i] = 1 (self loop)
__global__ __launch_bounds__(256) void init_deg_kernel(float* deg, int n) {
    int i = blockIdx.x * 256 + threadIdx.x;
    if (i < n) deg[i] = 1.0f;
}

__global__ __launch_bounds__(256) void edge_deg_kernel(const void* ei, const int* flag,
                                                       float* deg, int E) {
    int e = blockIdx.x * 256 + threadIdx.x;
    if (e >= E) return;
    int is64 = flag[0];
    int d = edge_get(ei, is64, (size_t)E + e);
    atomicAdd(&deg[d], 1.0f);
}

// in-place deg -> 1/sqrt(deg)
__global__ __launch_bounds__(256) void dinv_kernel(float* deg, int n) {
    int i = blockIdx.x * 256 + threadIdx.x;
    if (i < n) deg[i] = rsqrtf(deg[i]);
}

// ---------------------------------------------------------------------------
// C[n,128] = A[n,128] @ W[128,128].  W fully in LDS (64KB), 32-row A tile.
// 256 thr: thread = (rg 0..7, cg 0..31) computes 4 rows x 4 cols.
// ---------------------------------------------------------------------------
__global__ __launch_bounds__(256) void gemm_kernel(const float* __restrict__ A,
                                                   const float* __restrict__ W,
                                                   float* __restrict__ C, int n) {
    __shared__ float Ws[FD * FD];
    __shared__ float As[32 * FD];
    int tid = threadIdx.x;
    int row0 = blockIdx.x * 32;
    {
        float4* d = (float4*)Ws;
        const float4* s = (const float4*)W;
        for (int i = tid; i < FD * FD / 4; i += 256) d[i] = s[i];
    }
    {
        float4* d = (float4*)As;
        const float4* s = (const float4*)(A + (size_t)row0 * FD);
        int lim = (n - row0 < 32 ? n - row0 : 32) * (FD / 4);
        for (int i = tid; i < 32 * FD / 4; i += 256)
            d[i] = (i < lim) ? s[i] : make_float4(0.f, 0.f, 0.f, 0.f);
    }
    __syncthreads();

    int cg = tid & 31, rg = tid >> 5;
    const float* a0 = As + (rg * 4 + 0) * FD;
    const float* a1 = As + (rg * 4 + 1) * FD;
    const float* a2 = As + (rg * 4 + 2) * FD;
    const float* a3 = As + (rg * 4 + 3) * FD;
    const float4* Wv = (const float4*)Ws;
    float4 c0 = {0,0,0,0}, c1 = {0,0,0,0}, c2 = {0,0,0,0}, c3 = {0,0,0,0};
#pragma unroll 8
    for (int k = 0; k < FD; ++k) {
        float4 w = Wv[k * 32 + cg];
        float x0 = a0[k], x1 = a1[k], x2 = a2[k], x3 = a3[k];
        c0.x += x0 * w.x; c0.y += x0 * w.y; c0.z += x0 * w.z; c0.w += x0 * w.w;
        c1.x += x1 * w.x; c1.y += x1 * w.y; c1.z += x1 * w.z; c1.w += x1 * w.w;
        c2.x += x2 * w.x; c2.y += x2 * w.y; c2.z += x2 * w.z; c2.w += x2 * w.w;
        c3.x += x3 * w.x; c3.y += x3 * w.y; c3.z += x3 * w.z; c3.w += x3 * w.w;
    }
    int r = row0 + rg * 4;
    if (r + 0 < n) *(float4*)(C + (size_t)(r + 0) * FD + cg * 4) = c0;
    if (r + 1 < n) *(float4*)(C + (size_t)(r + 1) * FD + cg * 4) = c1;
    if (r + 2 < n) *(float4*)(C + (size_t)(r + 2) * FD + cg * 4) = c2;
    if (r + 3 < n) *(float4*)(C + (size_t)(r + 3) * FD + cg * 4) = c3;
}

// agg[i][f] = b[f] + h[i][f] * dinv[i]^2   (self-loop term + bias)
__global__ __launch_bounds__(256) void init_agg_kernel(const float* __restrict__ h,
                                                       const float* __restrict__ dinv,
                                                       const float* __restrict__ b,
                                                       float* __restrict__ agg, int n) {
    int t = blockIdx.x * 256 + threadIdx.x;
    if (t >= n * (FD / 4)) return;
    int r = t >> 5, c4 = t & 31;
    float w = dinv[r]; w *= w;
    float4 v = ((const float4*)h)[t];
    float4 bb = ((const float4*)b)[c4];
    float4 o;
    o.x = v.x * w + bb.x; o.y = v.y * w + bb.y;
    o.z = v.z * w + bb.z; o.w = v.w * w + bb.w;
    ((float4*)agg)[t] = o;
}

// per edge: agg[dst] += h[src] * dinv[src]*dinv[dst]   (32 threads/edge, float4)
__global__ __launch_bounds__(256) void scatter_kernel(const void* ei, const int* flag,
                                                      const float* __restrict__ h,
                                                      const float* __restrict__ dinv,
                                                      float* __restrict__ agg, int E) {
    int t = blockIdx.x * 256 + threadIdx.x;
    int e = t >> 5;
    if (e >= E) return;
    int f4 = t & 31;
    int is64 = flag[0];
    int s, d;
    if (is64) {
        const long long* p = (const long long*)ei;
        s = (int)p[e]; d = (int)p[(size_t)E + e];
    } else {
        const int* p = (const int*)ei;
        s = p[e]; d = p[E + e];
    }
    float nrm = dinv[s] * dinv[d];
    float4 v = *(const float4*)(h + (size_t)s * FD + f4 * 4);
    float* o = agg + (size_t)d * FD + f4 * 4;
    atomicAdd(o + 0, v.x * nrm);
    atomicAdd(o + 1, v.y * nrm);
    atomicAdd(o + 2, v.z * nrm);
    atomicAdd(o + 3, v.w * nrm);
}

__global__ __launch_bounds__(256) void zero_stats_kernel(float* stats) {
    stats[threadIdx.x] = 0.0f;
}

// column sums / sumsq over rows
__global__ __launch_bounds__(256) void bn_stats_kernel(const float* __restrict__ agg,
                                                       float* __restrict__ stats, int n) {
    int tid = threadIdx.x;
    int c = tid & 127;
    int r0 = blockIdx.x * 2 + (tid >> 7);
    int stride = gridDim.x * 2;
    float s = 0.f, ss = 0.f;
    for (int r = r0; r < n; r += stride) {
        float v = agg[(size_t)r * FD + c];
        s += v; ss += v * v;
    }
    atomicAdd(&stats[c], s);
    atomicAdd(&stats[FD + c], ss);
}

// scale/shift per column
__global__ __launch_bounds__(128) void bn_finalize_kernel(float* stats,
                                                          const float* __restrict__ g,
                                                          const float* __restrict__ be,
                                                          float invn) {
    int c = threadIdx.x;
    float mu = stats[c] * invn;
    float var = stats[FD + c] * invn - mu * mu;
    float sc = g[c] * rsqrtf(var + BN_EPS);
    stats[2 * FD + c] = sc;
    stats[3 * FD + c] = be[c] - mu * sc;
}

// out = prelu(agg*scale + shift)
__global__ __launch_bounds__(256) void bn_apply_kernel(const float* __restrict__ agg,
                                                       const float* __restrict__ stats,
                                                       const float* __restrict__ aP,
                                                       float* __restrict__ out, int n) {
    int t = blockIdx.x * 256 + threadIdx.x;
    if (t >= n * (FD / 4)) return;
    int c4 = t & 31;
    float alpha = aP[0];
    float4 v = ((const float4*)agg)[t];
    float4 sc = ((const float4*)(stats + 2 * FD))[c4];
    float4 sh = ((const float4*)(stats + 3 * FD))[c4];
    float4 y;
    y.x = v.x * sc.x + sh.x; y.y = v.y * sc.y + sh.y;
    y.z = v.z * sc.z + sh.z; y.w = v.w * sc.w + sh.w;
    y.x = y.x >= 0.f ? y.x : alpha * y.x;
    y.y = y.y >= 0.f ? y.y : alpha * y.y;
    y.z = y.z >= 0.f ? y.z : alpha * y.z;
    y.w = y.w >= 0.f ? y.w : alpha * y.w;
    ((float4*)out)[t] = y;
}

// ---------------------------------------------------------------------------

static void run_layer(const float* in, float* hbuf, float* abuf, float* outp,
                      const void* ei, const int* flag, const float* dinv, float* stats,
                      const float* W, const float* b, const float* g,
                      const float* be, const float* a,
                      int N, int E, hipStream_t stream) {
    int gemm_blocks = (N + 31) / 32;
    gemm_kernel<<<gemm_blocks, 256, 0, stream>>>(in, W, hbuf, N);

    int nt_nodes = N * (FD / 4);
    init_agg_kernel<<<(nt_nodes + 255) / 256, 256, 0, stream>>>(hbuf, dinv, b, abuf, N);

    long long nt_edges = (long long)E * 32;
    scatter_kernel<<<(int)((nt_edges + 255) / 256), 256, 0, stream>>>(ei, flag, hbuf,
                                                                      dinv, abuf, E);

    zero_stats_kernel<<<1, 256, 0, stream>>>(stats);
    bn_stats_kernel<<<400, 256, 0, stream>>>(abuf, stats, N);
    bn_finalize_kernel<<<1, 128, 0, stream>>>(stats, g, be, 1.0f / (float)N);
    bn_apply_kernel<<<(nt_nodes + 255) / 256, 256, 0, stream>>>(abuf, stats, a, outp, N);
}

extern "C" void kernel_launch(void* const* d_in, const int* in_sizes, int n_in,
                              void* d_out, int out_size, void* d_ws, size_t ws_size,
                              hipStream_t stream) {
    const float* x  = (const float*)d_in[0];
    const void*  ei = d_in[1];
    const float* W1 = (const float*)d_in[2];
    const float* b1 = (const float*)d_in[3];
    const float* g1 = (const float*)d_in[4];
    const float* be1= (const float*)d_in[5];
    const float* a1 = (const float*)d_in[6];
    const float* W2 = (const float*)d_in[7];
    const float* b2 = (const float*)d_in[8];
    const float* g2 = (const float*)d_in[9];
    const float* be2= (const float*)d_in[10];
    const float* a2 = (const float*)d_in[11];

    int N = in_sizes[0] / FD;
    int E = in_sizes[1] / 2;
    float* out = (float*)d_out;

    char* ws = (char*)d_ws;
    size_t off = 0;
    float* dinv = (float*)(ws + off);  off += (((size_t)N * 4 + 255) & ~(size_t)255);
    float* stats = (float*)(ws + off); off += 512 * 4;
    int*   flag = (int*)(ws + off);    off += 256;
    float* h    = (float*)(ws + off);  off += (size_t)N * FD * 4;
    float* agg  = (float*)(ws + off);  off += (size_t)N * FD * 4;
    (void)ws_size; (void)n_in; (void)out_size;

    // edge-index format probe (int32 vs int64)
    detect_kernel<<<1, 256, 0, stream>>>((const int*)ei, 2 * E, flag);

    // normalization: dinv = 1/sqrt(1 + indeg)
    init_deg_kernel<<<(N + 255) / 256, 256, 0, stream>>>(dinv, N);
    edge_deg_kernel<<<(E + 255) / 256, 256, 0, stream>>>(ei, flag, dinv, E);
    dinv_kernel<<<(N + 255) / 256, 256, 0, stream>>>(dinv, N);

    // layer 1: x -> h (gemm out h, agg in 'agg', BN result back into h)
    run_layer(x, h, agg, h, ei, flag, dinv, stats, W1, b1, g1, be1, a1, N, E, stream);
    // layer 2: h -> out (gemm out 'agg', agg target 'h', BN result -> d_out)
    run_layer(h, agg, h, out, ei, flag, dinv, stats, W2, b2, g2, be2, a2, N, E, stream);
}

// Round 2
// 386.217 us; speedup vs baseline: 7.6112x; 7.6112x over previous
//
#include <hip/hip_runtime.h>

#define FD 128
#define BN_EPS 1e-5f
#define NB_SCAN 256   // max scan blocks supported (N <= 256*256)

// ---------------------------------------------------------------------------
// Edge-index format probe (int32 vs int64), deterministic.
// ---------------------------------------------------------------------------
__global__ __launch_bounds__(256) void detect_kernel(const int* __restrict__ ei,
                                                     int n32, int* flag) {
    __shared__ int any;
    if (threadIdx.x == 0) any = 0;
    __syncthreads();
    int limit = n32 < 4096 ? n32 : 4096;
    int found = 0;
    for (int i = threadIdx.x * 2 + 1; i < limit; i += 512) {
        if (ei[i] != 0) { found = 1; break; }
    }
    if (found) atomicOr(&any, 1);
    __syncthreads();
    if (threadIdx.x == 0) flag[0] = any ? 0 : 1;   // 1 => int64 layout
}

__device__ __forceinline__ int edge_get(const void* ei, int is64, size_t idx) {
    return is64 ? (int)((const long long*)ei)[idx] : ((const int*)ei)[idx];
}

// ---------------------------------------------------------------------------
// CSR build: indeg histogram -> block scan -> fill
// ---------------------------------------------------------------------------
__global__ __launch_bounds__(256) void zero_indeg_kernel(int* indeg, int n) {
    int i = blockIdx.x * 256 + threadIdx.x;
    if (i < n) indeg[i] = 0;
}

__global__ __launch_bounds__(256) void edge_count_kernel(const void* ei, const int* flag,
                                                         int* indeg, int E) {
    int e = blockIdx.x * 256 + threadIdx.x;
    if (e >= E) return;
    int d = edge_get(ei, flag[0], (size_t)E + e);
    atomicAdd(&indeg[d], 1);
}

__global__ __launch_bounds__(256) void dinv_kernel(const int* __restrict__ indeg,
                                                   float* __restrict__ dinv, int n) {
    int i = blockIdx.x * 256 + threadIdx.x;
    if (i < n) dinv[i] = rsqrtf(1.0f + (float)indeg[i]);
}

// per-block exclusive scan of indeg (256 elems/block) -> rowptr (local), blockSums
__global__ __launch_bounds__(256) void scan1_kernel(const int* __restrict__ indeg,
                                                    int* __restrict__ rowptr,
                                                    int* __restrict__ blockSums, int n) {
    __shared__ int tmp[256];
    int t = threadIdx.x;
    int idx = blockIdx.x * 256 + t;
    int v = (idx < n) ? indeg[idx] : 0;
    tmp[t] = v;
    __syncthreads();
    for (int off = 1; off < 256; off <<= 1) {
        int x = (t >= off) ? tmp[t - off] : 0;
        __syncthreads();
        tmp[t] += x;
        __syncthreads();
    }
    if (idx < n) rowptr[idx] = tmp[t] - v;       // exclusive, no global offset yet
    if (t == 255) blockSums[blockIdx.x] = tmp[255];
}

// add global offsets; mirror into cursor; write rowptr[N]=E
__global__ __launch_bounds__(256) void scan2_kernel(int* __restrict__ rowptr,
                                                    int* __restrict__ cursor,
                                                    const int* __restrict__ blockSums,
                                                    int n, int E) {
    __shared__ int bs[NB_SCAN];
    int t = threadIdx.x;
    int nb = gridDim.x;
    bs[t] = (t < nb) ? blockSums[t] : 0;
    __syncthreads();
    int offset = 0;
    for (int j = 0; j < blockIdx.x; ++j) offset += bs[j];
    int idx = blockIdx.x * 256 + t;
    if (idx < n) {
        int r = rowptr[idx] + offset;
        rowptr[idx] = r;
        cursor[idx] = r;
    }
    if (blockIdx.x == 0 && t == 0) rowptr[n] = E;
}

__global__ __launch_bounds__(256) void fill_kernel(const void* ei, const int* flag,
                                                   int* __restrict__ cursor,
                                                   int* __restrict__ col, int E) {
    int e = blockIdx.x * 256 + threadIdx.x;
    if (e >= E) return;
    int is64 = flag[0];
    int s = edge_get(ei, is64, e);
    int d = edge_get(ei, is64, (size_t)E + e);
    int pos = atomicAdd(&cursor[d], 1);
    col[pos] = s;
}

// ---------------------------------------------------------------------------
// C[n,128] = A[n,128] @ W[128,128].  W fully in LDS, 32-row A tile.
// ---------------------------------------------------------------------------
__global__ __launch_bounds__(256) void gemm_kernel(const float* __restrict__ A,
                                                   const float* __restrict__ W,
                                                   float* __restrict__ C, int n) {
    __shared__ float Ws[FD * FD];
    __shared__ float As[32 * FD];
    int tid = threadIdx.x;
    int row0 = blockIdx.x * 32;
    {
        float4* d = (float4*)Ws;
        const float4* s = (const float4*)W;
        for (int i = tid; i < FD * FD / 4; i += 256) d[i] = s[i];
    }
    {
        float4* d = (float4*)As;
        const float4* s = (const float4*)(A + (size_t)row0 * FD);
        int lim = (n - row0 < 32 ? n - row0 : 32) * (FD / 4);
        for (int i = tid; i < 32 * FD / 4; i += 256)
            d[i] = (i < lim) ? s[i] : make_float4(0.f, 0.f, 0.f, 0.f);
    }
    __syncthreads();

    int cg = tid & 31, rg = tid >> 5;
    const float* a0 = As + (rg * 4 + 0) * FD;
    const float* a1 = As + (rg * 4 + 1) * FD;
    const float* a2 = As + (rg * 4 + 2) * FD;
    const float* a3 = As + (rg * 4 + 3) * FD;
    const float4* Wv = (const float4*)Ws;
    float4 c0 = {0,0,0,0}, c1 = {0,0,0,0}, c2 = {0,0,0,0}, c3 = {0,0,0,0};
#pragma unroll 8
    for (int k = 0; k < FD; ++k) {
        float4 w = Wv[k * 32 + cg];
        float x0 = a0[k], x1 = a1[k], x2 = a2[k], x3 = a3[k];
        c0.x += x0 * w.x; c0.y += x0 * w.y; c0.z += x0 * w.z; c0.w += x0 * w.w;
        c1.x += x1 * w.x; c1.y += x1 * w.y; c1.z += x1 * w.z; c1.w += x1 * w.w;
        c2.x += x2 * w.x; c2.y += x2 * w.y; c2.z += x2 * w.z; c2.w += x2 * w.w;
        c3.x += x3 * w.x; c3.y += x3 * w.y; c3.z += x3 * w.z; c3.w += x3 * w.w;
    }
    int r = row0 + rg * 4;
    if (r + 0 < n) *(float4*)(C + (size_t)(r + 0) * FD + cg * 4) = c0;
    if (r + 1 < n) *(float4*)(C + (size_t)(r + 1) * FD + cg * 4) = c1;
    if (r + 2 < n) *(float4*)(C + (size_t)(r + 2) * FD + cg * 4) = c2;
    if (r + 3 < n) *(float4*)(C + (size_t)(r + 3) * FD + cg * 4) = c3;
}

// ---------------------------------------------------------------------------
// CSR gather aggregation: one wave (64 lanes) per dst node, float2/lane.
// agg[d] = dinv[d]*( sum_{s in N(d)} dinv[s]*h[s] + dinv[d]*h[d] ) + bias
// ---------------------------------------------------------------------------
__global__ __launch_bounds__(256) void gather_kernel(const float* __restrict__ h,
                                                     const int* __restrict__ rowptr,
                                                     const int* __restrict__ col,
                                                     const float* __restrict__ dinv,
                                                     const float* __restrict__ b,
                                                     float* __restrict__ agg, int n) {
    int wid = (blockIdx.x * 256 + threadIdx.x) >> 6;   // node index
    int lane = threadIdx.x & 63;
    if (wid >= n) return;
    const float2* hb = (const float2*)h;
    float dv = dinv[wid];
    size_t base = (size_t)wid * 64 + lane;
    float2 self = hb[base];
    float2 acc;
    acc.x = dv * self.x;
    acc.y = dv * self.y;
    int i = rowptr[wid], end = rowptr[wid + 1];
    for (; i + 4 <= end; i += 4) {
        int s0 = col[i], s1 = col[i + 1], s2 = col[i + 2], s3 = col[i + 3];
        float w0 = dinv[s0], w1 = dinv[s1], w2 = dinv[s2], w3 = dinv[s3];
        float2 v0 = hb[(size_t)s0 * 64 + lane];
        float2 v1 = hb[(size_t)s1 * 64 + lane];
        float2 v2 = hb[(size_t)s2 * 64 + lane];
        float2 v3 = hb[(size_t)s3 * 64 + lane];
        acc.x += w0 * v0.x; acc.y += w0 * v0.y;
        acc.x += w1 * v1.x; acc.y += w1 * v1.y;
        acc.x += w2 * v2.x; acc.y += w2 * v2.y;
        acc.x += w3 * v3.x; acc.y += w3 * v3.y;
    }
    for (; i < end; ++i) {
        int s = col[i];
        float w = dinv[s];
        float2 v = hb[(size_t)s * 64 + lane];
        acc.x += w * v.x; acc.y += w * v.y;
    }
    float2 bb = ((const float2*)b)[lane];
    float2 o;
    o.x = dv * acc.x + bb.x;
    o.y = dv * acc.y + bb.y;
    ((float2*)agg)[base] = o;
}

// ---------------------------------------------------------------------------
// BatchNorm + PReLU
// ---------------------------------------------------------------------------
__global__ __launch_bounds__(256) void zero_stats_kernel(float* stats) {
    stats[threadIdx.x] = 0.0f;
}

__global__ __launch_bounds__(256) void bn_stats_kernel(const float* __restrict__ agg,
                                                       float* __restrict__ stats, int n) {
    int tid = threadIdx.x;
    int c = tid & 127;
    int r0 = blockIdx.x * 2 + (tid >> 7);
    int stride = gridDim.x * 2;
    float s = 0.f, ss = 0.f;
    for (int r = r0; r < n; r += stride) {
        float v = agg[(size_t)r * FD + c];
        s += v; ss += v * v;
    }
    atomicAdd(&stats[c], s);
    atomicAdd(&stats[FD + c], ss);
}

__global__ __launch_bounds__(128) void bn_finalize_kernel(float* stats,
                                                          const float* __restrict__ g,
                                                          const float* __restrict__ be,
                                                          float invn) {
    int c = threadIdx.x;
    float mu = stats[c] * invn;
    float var = stats[FD + c] * invn - mu * mu;
    float sc = g[c] * rsqrtf(var + BN_EPS);
    stats[2 * FD + c] = sc;
    stats[3 * FD + c] = be[c] - mu * sc;
}

__global__ __launch_bounds__(256) void bn_apply_kernel(const float* __restrict__ agg,
                                                       const float* __restrict__ stats,
                                                       const float* __restrict__ aP,
                                                       float* __restrict__ out, int n) {
    int t = blockIdx.x * 256 + threadIdx.x;
    if (t >= n * (FD / 4)) return;
    int c4 = t & 31;
    float alpha = aP[0];
    float4 v = ((const float4*)agg)[t];
    float4 sc = ((const float4*)(stats + 2 * FD))[c4];
    float4 sh = ((const float4*)(stats + 3 * FD))[c4];
    float4 y;
    y.x = v.x * sc.x + sh.x; y.y = v.y * sc.y + sh.y;
    y.z = v.z * sc.z + sh.z; y.w = v.w * sc.w + sh.w;
    y.x = y.x >= 0.f ? y.x : alpha * y.x;
    y.y = y.y >= 0.f ? y.y : alpha * y.y;
    y.z = y.z >= 0.f ? y.z : alpha * y.z;
    y.w = y.w >= 0.f ? y.w : alpha * y.w;
    ((float4*)out)[t] = y;
}

// ---------------------------------------------------------------------------

static void run_layer(const float* in, float* hbuf, float* abuf, float* outp,
                      const int* rowptr, const int* colA, const float* dinv,
                      float* stats, const float* W, const float* b, const float* g,
                      const float* be, const float* a,
                      int N, hipStream_t stream) {
    gemm_kernel<<<(N + 31) / 32, 256, 0, stream>>>(in, W, hbuf, N);
    gather_kernel<<<(N * 64 + 255) / 256, 256, 0, stream>>>(hbuf, rowptr, colA, dinv,
                                                            b, abuf, N);
    zero_stats_kernel<<<1, 256, 0, stream>>>(stats);
    bn_stats_kernel<<<400, 256, 0, stream>>>(abuf, stats, N);
    bn_finalize_kernel<<<1, 128, 0, stream>>>(stats, g, be, 1.0f / (float)N);
    int nt = N * (FD / 4);
    bn_apply_kernel<<<(nt + 255) / 256, 256, 0, stream>>>(abuf, stats, a, outp, N);
}

extern "C" void kernel_launch(void* const* d_in, const int* in_sizes, int n_in,
                              void* d_out, int out_size, void* d_ws, size_t ws_size,
                              hipStream_t stream) {
    const float* x  = (const float*)d_in[0];
    const void*  ei = d_in[1];
    const float* W1 = (const float*)d_in[2];
    const float* b1 = (const float*)d_in[3];
    const float* g1 = (const float*)d_in[4];
    const float* be1= (const float*)d_in[5];
    const float* a1 = (const float*)d_in[6];
    const float* W2 = (const float*)d_in[7];
    const float* b2 = (const float*)d_in[8];
    const float* g2 = (const float*)d_in[9];
    const float* be2= (const float*)d_in[10];
    const float* a2 = (const float*)d_in[11];

    int N = in_sizes[0] / FD;
    int E = in_sizes[1] / 2;
    float* out = (float*)d_out;

    char* ws = (char*)d_ws;
    size_t off = 0;
    auto alloc = [&](size_t bytes) {
        void* p = ws + off;
        off += (bytes + 255) & ~(size_t)255;
        return p;
    };
    float* dinv    = (float*)alloc((size_t)N * 4);
    float* stats   = (float*)alloc(512 * 4);
    int*   flag    = (int*)alloc(256);
    int*   indeg   = (int*)alloc((size_t)N * 4);
    int*   rowptr  = (int*)alloc(((size_t)N + 1) * 4);
    int*   cursor  = (int*)alloc((size_t)N * 4);
    int*   bsums   = (int*)alloc(NB_SCAN * 4);
    int*   colA    = (int*)alloc((size_t)E * 4);
    float* h       = (float*)alloc((size_t)N * FD * 4);
    float* agg     = (float*)alloc((size_t)N * FD * 4);
    (void)ws_size; (void)n_in; (void)out_size;

    int nbN = (N + 255) / 256;   // 196 for N=50000 (<= NB_SCAN)
    int nbE = (E + 255) / 256;

    detect_kernel<<<1, 256, 0, stream>>>((const int*)ei, 2 * E, flag);

    // CSR build (once; reused by both layers)
    zero_indeg_kernel<<<nbN, 256, 0, stream>>>(indeg, N);
    edge_count_kernel<<<nbE, 256, 0, stream>>>(ei, flag, indeg, E);
    dinv_kernel<<<nbN, 256, 0, stream>>>(indeg, dinv, N);
    scan1_kernel<<<nbN, 256, 0, stream>>>(indeg, rowptr, bsums, N);
    scan2_kernel<<<nbN, 256, 0, stream>>>(rowptr, cursor, bsums, N, E);
    fill_kernel<<<nbE, 256, 0, stream>>>(ei, flag, cursor, colA, E);

    // layer 1: x -> h(gemm) -> agg -> BN/PReLU back into h
    run_layer(x, h, agg, h, rowptr, colA, dinv, stats, W1, b1, g1, be1, a1, N, stream);
    // layer 2: h -> agg(gemm) -> h(agg target) ... BN/PReLU -> d_out
    run_layer(h, agg, h, out, rowptr, colA, dinv, stats, W2, b2, g2, be2, a2, N, stream);
}

// Round 3
// 297.059 us; speedup vs baseline: 9.8955x; 1.3001x over previous
//
#include <hip/hip_runtime.h>

#define FD 128
#define BN_EPS 1e-5f
#define NB_SCAN 256   // max scan blocks supported (N <= 256*256)

typedef short s8v __attribute__((ext_vector_type(8)));    // 8 bf16 bit-patterns
typedef float f4v __attribute__((ext_vector_type(4)));

__device__ __forceinline__ unsigned short f2bf(float f) {
    unsigned u = __float_as_uint(f);
    u += 0x7fff + ((u >> 16) & 1);           // RNE
    return (unsigned short)(u >> 16);
}
__device__ __forceinline__ float bf_lo(unsigned int u) {
    return __uint_as_float(u << 16);
}
__device__ __forceinline__ float bf_hi(unsigned int u) {
    return __uint_as_float(u & 0xffff0000u);
}

// ---------------------------------------------------------------------------
// Edge-index format probe (int32 vs int64), deterministic.
// ---------------------------------------------------------------------------
__global__ __launch_bounds__(256) void detect_kernel(const int* __restrict__ ei,
                                                     int n32, int* flag) {
    __shared__ int any;
    if (threadIdx.x == 0) any = 0;
    __syncthreads();
    int limit = n32 < 4096 ? n32 : 4096;
    int found = 0;
    for (int i = threadIdx.x * 2 + 1; i < limit; i += 512) {
        if (ei[i] != 0) { found = 1; break; }
    }
    if (found) atomicOr(&any, 1);
    __syncthreads();
    if (threadIdx.x == 0) flag[0] = any ? 0 : 1;   // 1 => int64 layout
}

__device__ __forceinline__ int edge_get(const void* ei, int is64, size_t idx) {
    return is64 ? (int)((const long long*)ei)[idx] : ((const int*)ei)[idx];
}

// ---------------------------------------------------------------------------
// CSR build: indeg histogram -> block scan -> fill
// ---------------------------------------------------------------------------
__global__ __launch_bounds__(256) void zero_indeg_kernel(int* indeg, int n) {
    int i = blockIdx.x * 256 + threadIdx.x;
    if (i < n) indeg[i] = 0;
}

__global__ __launch_bounds__(256) void edge_count_kernel(const void* ei, const int* flag,
                                                         int* indeg, int E) {
    int e = blockIdx.x * 256 + threadIdx.x;
    if (e >= E) return;
    int d = edge_get(ei, flag[0], (size_t)E + e);
    atomicAdd(&indeg[d], 1);
}

__global__ __launch_bounds__(256) void dinv_kernel(const int* __restrict__ indeg,
                                                   float* __restrict__ dinv, int n) {
    int i = blockIdx.x * 256 + threadIdx.x;
    if (i < n) dinv[i] = rsqrtf(1.0f + (float)indeg[i]);
}

__global__ __launch_bounds__(256) void scan1_kernel(const int* __restrict__ indeg,
                                                    int* __restrict__ rowptr,
                                                    int* __restrict__ blockSums, int n) {
    __shared__ int tmp[256];
    int t = threadIdx.x;
    int idx = blockIdx.x * 256 + t;
    int v = (idx < n) ? indeg[idx] : 0;
    tmp[t] = v;
    __syncthreads();
    for (int off = 1; off < 256; off <<= 1) {
        int x = (t >= off) ? tmp[t - off] : 0;
        __syncthreads();
        tmp[t] += x;
        __syncthreads();
    }
    if (idx < n) rowptr[idx] = tmp[t] - v;
    if (t == 255) blockSums[blockIdx.x] = tmp[255];
}

__global__ __launch_bounds__(256) void scan2_kernel(int* __restrict__ rowptr,
                                                    int* __restrict__ cursor,
                                                    const int* __restrict__ blockSums,
                                                    int n, int E) {
    __shared__ int bs[NB_SCAN];
    int t = threadIdx.x;
    int nb = gridDim.x;
    bs[t] = (t < nb) ? blockSums[t] : 0;
    __syncthreads();
    int offset = 0;
    for (int j = 0; j < blockIdx.x; ++j) offset += bs[j];
    int idx = blockIdx.x * 256 + t;
    if (idx < n) {
        int r = rowptr[idx] + offset;
        rowptr[idx] = r;
        cursor[idx] = r;
    }
    if (blockIdx.x == 0 && t == 0) rowptr[n] = E;
}

__global__ __launch_bounds__(256) void fill_kernel(const void* ei, const int* flag,
                                                   int* __restrict__ cursor,
                                                   int* __restrict__ col, int E) {
    int e = blockIdx.x * 256 + threadIdx.x;
    if (e >= E) return;
    int is64 = flag[0];
    int s = edge_get(ei, is64, e);
    int d = edge_get(ei, is64, (size_t)E + e);
    int pos = atomicAdd(&cursor[d], 1);
    col[pos] = s;
}

// ---------------------------------------------------------------------------
// W[128,128] f32 -> fragment-ordered bf16 for mfma_f32_16x16x32_bf16 B-operand.
// Wfrag[((kt*8+ct)*64 + lane)*8 + j] = bf16( W[kt*32 + (lane>>4)*8 + j][ct*16 + (lane&15)] )
// ---------------------------------------------------------------------------
__global__ __launch_bounds__(256) void wprep_kernel(const float* __restrict__ W,
                                                    unsigned short* __restrict__ Wfrag) {
    int idx = blockIdx.x * 256 + threadIdx.x;   // 16384 total
    int j = idx & 7, lane = (idx >> 3) & 63, ct = (idx >> 9) & 7, kt = idx >> 12;
    int k = kt * 32 + (lane >> 4) * 8 + j;
    int c = ct * 16 + (lane & 15);
    Wfrag[idx] = f2bf(W[k * FD + c]);
}

// ---------------------------------------------------------------------------
// C[n,128] = (A[n,128] @ W) * dinv[row], stored bf16.
// Block = 4 waves x 16 rows = 64 rows. No LDS; W frags from global (L2-resident).
// ---------------------------------------------------------------------------
template<int IN_BF16>
__global__ __launch_bounds__(256) void gemm_mfma_kernel(const void* __restrict__ Ain,
                                                        const unsigned short* __restrict__ Wfrag,
                                                        const float* __restrict__ dinv,
                                                        unsigned short* __restrict__ C,
                                                        int n) {
    int wave = threadIdx.x >> 6, lane = threadIdx.x & 63;
    int rbase = blockIdx.x * 64 + wave * 16;
    int lrow = rbase + (lane & 15);
    int kg = lane >> 4;
    bool rok = lrow < n;

    f4v acc[8];
#pragma unroll
    for (int i = 0; i < 8; ++i) acc[i] = (f4v){0.f, 0.f, 0.f, 0.f};

    const s8v* wf = (const s8v*)Wfrag;

#pragma unroll
    for (int kt = 0; kt < 4; ++kt) {
        s8v afr = (s8v){0, 0, 0, 0, 0, 0, 0, 0};
        if (rok) {
            if (IN_BF16) {
                const unsigned short* A = (const unsigned short*)Ain;
                afr = *(const s8v*)(A + (size_t)lrow * FD + kt * 32 + kg * 8);
            } else {
                const float* A = (const float*)Ain;
                const float* p = A + (size_t)lrow * FD + kt * 32 + kg * 8;
                float4 u0 = *(const float4*)p;
                float4 u1 = *(const float4*)(p + 4);
                afr[0] = (short)f2bf(u0.x); afr[1] = (short)f2bf(u0.y);
                afr[2] = (short)f2bf(u0.z); afr[3] = (short)f2bf(u0.w);
                afr[4] = (short)f2bf(u1.x); afr[5] = (short)f2bf(u1.y);
                afr[6] = (short)f2bf(u1.z); afr[7] = (short)f2bf(u1.w);
            }
        }
#pragma unroll
        for (int ct = 0; ct < 8; ++ct) {
            s8v bfr = wf[(kt * 8 + ct) * 64 + lane];
            acc[ct] = __builtin_amdgcn_mfma_f32_16x16x32_bf16(afr, bfr, acc[ct], 0, 0, 0);
        }
    }

    // C/D layout: col = lane&15, row = (lane>>4)*4 + r
    int col0 = lane & 15;
#pragma unroll
    for (int r = 0; r < 4; ++r) {
        int row = rbase + kg * 4 + r;
        if (row < n) {
            float dv = dinv[row];
            unsigned short* crow = C + (size_t)row * FD;
#pragma unroll
            for (int ct = 0; ct < 8; ++ct)
                crow[ct * 16 + col0] = f2bf(acc[ct][r] * dv);
        }
    }
}

// ---------------------------------------------------------------------------
// CSR gather: one wave per dst node, 2 bf16 per lane.
// hs[r] = dinv[r] * h[r]  (pre-scaled by gemm epilogue)
// agg[d] = dinv[d] * ( sum_{s in N(d)} hs[s] + hs[d] ) + bias
// ---------------------------------------------------------------------------
__global__ __launch_bounds__(256) void gather_kernel(const unsigned int* __restrict__ hs,
                                                     const int* __restrict__ rowptr,
                                                     const int* __restrict__ col,
                                                     const float* __restrict__ dinv,
                                                     const float* __restrict__ b,
                                                     float* __restrict__ agg, int n) {
    int wid = (blockIdx.x * 256 + threadIdx.x) >> 6;
    int lane = threadIdx.x & 63;
    if (wid >= n) return;
    float dv = dinv[wid];
    size_t base = (size_t)wid * 64 + lane;
    unsigned int u = hs[base];                 // self term
    float ax = bf_lo(u), ay = bf_hi(u);
    int i = rowptr[wid], end = rowptr[wid + 1];
    for (; i + 4 <= end; i += 4) {
        int s0 = col[i], s1 = col[i + 1], s2 = col[i + 2], s3 = col[i + 3];
        unsigned int v0 = hs[(size_t)s0 * 64 + lane];
        unsigned int v1 = hs[(size_t)s1 * 64 + lane];
        unsigned int v2 = hs[(size_t)s2 * 64 + lane];
        unsigned int v3 = hs[(size_t)s3 * 64 + lane];
        ax += bf_lo(v0) + bf_lo(v1) + bf_lo(v2) + bf_lo(v3);
        ay += bf_hi(v0) + bf_hi(v1) + bf_hi(v2) + bf_hi(v3);
    }
    for (; i < end; ++i) {
        unsigned int v = hs[(size_t)col[i] * 64 + lane];
        ax += bf_lo(v);
        ay += bf_hi(v);
    }
    float2 bb = ((const float2*)b)[lane];
    float2 o;
    o.x = dv * ax + bb.x;
    o.y = dv * ay + bb.y;
    ((float2*)agg)[base] = o;
}

// ---------------------------------------------------------------------------
// BatchNorm + PReLU
// ---------------------------------------------------------------------------
__global__ __launch_bounds__(256) void zero_stats_kernel(float* stats) {
    stats[threadIdx.x] = 0.0f;
}

__global__ __launch_bounds__(256) void bn_stats_kernel(const float* __restrict__ agg,
                                                       float* __restrict__ stats, int n) {
    int tid = threadIdx.x;
    int c = tid & 127;
    int r0 = blockIdx.x * 2 + (tid >> 7);
    int stride = gridDim.x * 2;
    float s = 0.f, ss = 0.f;
    for (int r = r0; r < n; r += stride) {
        float v = agg[(size_t)r * FD + c];
        s += v; ss += v * v;
    }
    atomicAdd(&stats[c], s);
    atomicAdd(&stats[FD + c], ss);
}

__global__ __launch_bounds__(128) void bn_finalize_kernel(float* stats,
                                                          const float* __restrict__ g,
                                                          const float* __restrict__ be,
                                                          float invn) {
    int c = threadIdx.x;
    float mu = stats[c] * invn;
    float var = stats[FD + c] * invn - mu * mu;
    float sc = g[c] * rsqrtf(var + BN_EPS);
    stats[2 * FD + c] = sc;
    stats[3 * FD + c] = be[c] - mu * sc;
}

// OUT_BF16=1: write bf16 (feeds next gemm); else f32 (final output)
template<int OUT_BF16>
__global__ __launch_bounds__(256) void bn_apply_kernel(const float* __restrict__ agg,
                                                       const float* __restrict__ stats,
                                                       const float* __restrict__ aP,
                                                       void* __restrict__ out, int n) {
    int t = blockIdx.x * 256 + threadIdx.x;
    if (t >= n * (FD / 4)) return;
    int c4 = t & 31;
    float alpha = aP[0];
    float4 v = ((const float4*)agg)[t];
    float4 sc = ((const float4*)(stats + 2 * FD))[c4];
    float4 sh = ((const float4*)(stats + 3 * FD))[c4];
    float4 y;
    y.x = v.x * sc.x + sh.x; y.y = v.y * sc.y + sh.y;
    y.z = v.z * sc.z + sh.z; y.w = v.w * sc.w + sh.w;
    y.x = y.x >= 0.f ? y.x : alpha * y.x;
    y.y = y.y >= 0.f ? y.y : alpha * y.y;
    y.z = y.z >= 0.f ? y.z : alpha * y.z;
    y.w = y.w >= 0.f ? y.w : alpha * y.w;
    if (OUT_BF16) {
        uint2 p;
        p.x = (unsigned)f2bf(y.x) | ((unsigned)f2bf(y.y) << 16);
        p.y = (unsigned)f2bf(y.z) | ((unsigned)f2bf(y.w) << 16);
        ((uint2*)out)[t] = p;
    } else {
        ((float4*)out)[t] = y;
    }
}

// ---------------------------------------------------------------------------

extern "C" void kernel_launch(void* const* d_in, const int* in_sizes, int n_in,
                              void* d_out, int out_size, void* d_ws, size_t ws_size,
                              hipStream_t stream) {
    const float* x  = (const float*)d_in[0];
    const void*  ei = d_in[1];
    const float* W1 = (const float*)d_in[2];
    const float* b1 = (const float*)d_in[3];
    const float* g1 = (const float*)d_in[4];
    const float* be1= (const float*)d_in[5];
    const float* a1 = (const float*)d_in[6];
    const float* W2 = (const float*)d_in[7];
    const float* b2 = (const float*)d_in[8];
    const float* g2 = (const float*)d_in[9];
    const float* be2= (const float*)d_in[10];
    const float* a2 = (const float*)d_in[11];

    int N = in_sizes[0] / FD;
    int E = in_sizes[1] / 2;
    float* out = (float*)d_out;

    char* ws = (char*)d_ws;
    size_t off = 0;
    auto alloc = [&](size_t bytes) {
        void* p = ws + off;
        off += (bytes + 255) & ~(size_t)255;
        return p;
    };
    float* dinv    = (float*)alloc((size_t)N * 4);
    float* stats   = (float*)alloc(512 * 4);
    int*   flag    = (int*)alloc(256);
    int*   indeg   = (int*)alloc((size_t)N * 4);
    int*   rowptr  = (int*)alloc(((size_t)N + 1) * 4);
    int*   cursor  = (int*)alloc((size_t)N * 4);
    int*   bsums   = (int*)alloc(NB_SCAN * 4);
    int*   colA    = (int*)alloc((size_t)E * 4);
    unsigned short* wf1 = (unsigned short*)alloc((size_t)FD * FD * 2);
    unsigned short* wf2 = (unsigned short*)alloc((size_t)FD * FD * 2);
    unsigned short* hs  = (unsigned short*)alloc((size_t)N * FD * 2);  // gemm out (bf16, pre-scaled)
    unsigned short* y1  = (unsigned short*)alloc((size_t)N * FD * 2);  // layer-1 bn out (bf16)
    float* agg     = (float*)alloc((size_t)N * FD * 4);
    (void)ws_size; (void)n_in; (void)out_size;

    int nbN = (N + 255) / 256;
    int nbE = (E + 255) / 256;

    detect_kernel<<<1, 256, 0, stream>>>((const int*)ei, 2 * E, flag);

    // CSR build (once; reused by both layers)
    zero_indeg_kernel<<<nbN, 256, 0, stream>>>(indeg, N);
    edge_count_kernel<<<nbE, 256, 0, stream>>>(ei, flag, indeg, E);
    dinv_kernel<<<nbN, 256, 0, stream>>>(indeg, dinv, N);
    scan1_kernel<<<nbN, 256, 0, stream>>>(indeg, rowptr, bsums, N);
    scan2_kernel<<<nbN, 256, 0, stream>>>(rowptr, cursor, bsums, N, E);
    fill_kernel<<<nbE, 256, 0, stream>>>(ei, flag, cursor, colA, E);

    // weight fragment prep (both layers)
    wprep_kernel<<<64, 256, 0, stream>>>(W1, wf1);
    wprep_kernel<<<64, 256, 0, stream>>>(W2, wf2);

    int gemm_blocks = (N + 63) / 64;
    int nt = N * (FD / 4);

    // ---- layer 1 ----
    gemm_mfma_kernel<0><<<gemm_blocks, 256, 0, stream>>>(x, wf1, dinv, hs, N);
    gather_kernel<<<(N * 64 + 255) / 256, 256, 0, stream>>>((const unsigned int*)hs,
                                                            rowptr, colA, dinv, b1, agg, N);
    zero_stats_kernel<<<1, 256, 0, stream>>>(stats);
    bn_stats_kernel<<<400, 256, 0, stream>>>(agg, stats, N);
    bn_finalize_kernel<<<1, 128, 0, stream>>>(stats, g1, be1, 1.0f / (float)N);
    bn_apply_kernel<1><<<(nt + 255) / 256, 256, 0, stream>>>(agg, stats, a1, y1, N);

    // ---- layer 2 ----
    gemm_mfma_kernel<1><<<gemm_blocks, 256, 0, stream>>>(y1, wf2, dinv, hs, N);
    gather_kernel<<<(N * 64 + 255) / 256, 256, 0, stream>>>((const unsigned int*)hs,
                                                            rowptr, colA, dinv, b2, agg, N);
    zero_stats_kernel<<<1, 256, 0, stream>>>(stats);
    bn_stats_kernel<<<400, 256, 0, stream>>>(agg, stats, N);
    bn_finalize_kernel<<<1, 128, 0, stream>>>(stats, g2, be2, 1.0f / (float)N);
    bn_apply_kernel<0><<<(nt + 255) / 256, 256, 0, stream>>>(agg, stats, a2, out, N);
}